// Round 2
// baseline (901.001 us; speedup 1.0000x reference)
//
#include <hip/hip_runtime.h>

#define N_USER 100000
#define N_ITEM 50000
#define N_NODES 150000
#define EMB 64
#define NNZ 4000000
#define BATCH 4096
#define NSLOTS (3 * BATCH)          // 12288 output slots

// ws layout (all offsets bytes, 256-aligned):
//   CNT_OFF : worklist counter (uint)
//   BM_OFF  : bitmask, 150000 bits -> 18752 B
//   CT_OFF  : node -> compact-id table, 150000 int32 (600000 B), init 0xFF (-1)
//   PROP_OFF: compact prop, 12288 x 64 f32 = 3.1 MB
//   WL_OFF  : worklist, up to NNZ uint2 (8 B each) = 32 MB
#define CNT_OFF  0
#define BM_OFF   256
#define CT_OFF   19200
#define PROP_OFF 619520
#define WL_OFF   3765504

// K1: one wave per output slot: set bitmask bit, claim a compact id for the
// node (first slot to CAS wins; compact ids are a subset of [0,NSLOTS)),
// and zero this slot's prop row (covers every winning compact id).
__global__ void mark_kernel(const int* __restrict__ users,
                            const int* __restrict__ pos_items,
                            const int* __restrict__ neg_items,
                            unsigned int* __restrict__ bitmask,
                            int* __restrict__ ctab,
                            float* __restrict__ prop) {
    int t = blockIdx.x * blockDim.x + threadIdx.x;
    int slot = t >> 6;                 // 12288 waves
    int lane = t & 63;
    int k = slot >> 12;
    int i = slot & 4095;
    int node;
    if (k == 0)      node = users[i];
    else if (k == 1) node = N_USER + pos_items[i];
    else             node = N_USER + neg_items[i];
    prop[(size_t)slot * EMB + lane] = 0.0f;
    if (lane == 0) {
        atomicOr(bitmask + (node >> 5), 1u << (node & 31));
        atomicCAS(ctab + node, -1, slot);
    }
}

// K2: filter 4M edges -> compacted worklist of needed edges.
// Bitmask (18.75 KB) is L1-resident, so the per-edge test is cheap.
__global__ void filter_kernel(const int* __restrict__ rows,
                              const int* __restrict__ cols,
                              const float* __restrict__ vals,
                              const unsigned int* __restrict__ bitmask,
                              const int* __restrict__ ctab,
                              unsigned int* __restrict__ counter,
                              uint2* __restrict__ wl) {
    int tid = blockIdx.x * blockDim.x + threadIdx.x;   // grid covers NNZ exactly
    int lane = threadIdx.x & 63;
    int row = rows[tid];
    int col = cols[tid];
    float val = vals[tid];
    unsigned int w = bitmask[row >> 5];
    bool needed = (w >> (row & 31)) & 1;
    unsigned long long mask = __ballot(needed);
    if (mask == 0ull) return;
    int cnt = __popcll(mask);
    int leader = __ffsll((unsigned long long)mask) - 1;
    unsigned int base = 0;
    if (lane == leader) base = atomicAdd(counter, (unsigned int)cnt);
    base = (unsigned int)__shfl((int)base, leader);
    if (needed) {
        int prefix = __popcll(mask & ((1ull << lane) - 1ull));
        int cid = ctab[row];                              // compact row id
        wl[base + prefix] = make_uint2(((unsigned int)cid << 18) | (unsigned int)col,
                                       __float_as_uint(val));
    }
}

// K3: persistent waves grid-stride the worklist; one edge per wave-iteration.
// Independent iterations -> latency hidden by pipelining, no serial mask walk.
#define APPLY_WAVES 4096
__global__ void apply_kernel(const uint2* __restrict__ wl,
                             const unsigned int* __restrict__ counter,
                             const float* __restrict__ user_emb,
                             const float* __restrict__ item_emb,
                             float* __restrict__ prop) {
    int t = blockIdx.x * blockDim.x + threadIdx.x;
    int wid = t >> 6;
    int lane = t & 63;
    unsigned int n = *counter;
    for (unsigned int i = wid; i < n; i += APPLY_WAVES) {
        uint2 e = wl[i];
        int cid = (int)(e.x >> 18);
        int col = (int)(e.x & 0x3FFFFu);
        float v = __uint_as_float(e.y);
        const float* x = (col < N_USER) ? (user_emb + (size_t)col * EMB)
                                        : (item_emb + (size_t)(col - N_USER) * EMB);
        atomicAdd(prop + (size_t)cid * EMB + lane, v * x[lane]);
    }
}

// K4: out[k][i][lane] = (ego + 3*prop)/4 at the sampled nodes (via compact id)
__global__ void gather_kernel(const int* __restrict__ users,
                              const int* __restrict__ pos_items,
                              const int* __restrict__ neg_items,
                              const float* __restrict__ user_emb,
                              const float* __restrict__ item_emb,
                              const int* __restrict__ ctab,
                              const float* __restrict__ prop,
                              float* __restrict__ out) {
    int t = blockIdx.x * blockDim.x + threadIdx.x;
    int slot = t >> 6;
    int lane = t & 63;
    int k = slot >> 12;
    int i = slot & 4095;
    int node;
    if (k == 0)      node = users[i];
    else if (k == 1) node = N_USER + pos_items[i];
    else             node = N_USER + neg_items[i];
    float ego = (node < N_USER)
                    ? user_emb[(size_t)node * EMB + lane]
                    : item_emb[(size_t)(node - N_USER) * EMB + lane];
    int cid = ctab[node];
    float p = prop[(size_t)cid * EMB + lane];
    out[t] = (ego + 3.0f * p) * 0.25f;
}

extern "C" void kernel_launch(void* const* d_in, const int* in_sizes, int n_in,
                              void* d_out, int out_size, void* d_ws, size_t ws_size,
                              hipStream_t stream) {
    const int*   adj_rows = (const int*)  d_in[0];
    const int*   adj_cols = (const int*)  d_in[1];
    const float* adj_vals = (const float*)d_in[2];
    const float* user_emb = (const float*)d_in[3];
    const float* item_emb = (const float*)d_in[4];
    const int*   users    = (const int*)  d_in[5];
    const int*   pos      = (const int*)  d_in[6];
    const int*   neg      = (const int*)  d_in[7];
    float* out = (float*)d_out;

    unsigned int* counter = (unsigned int*)((char*)d_ws + CNT_OFF);
    unsigned int* bitmask = (unsigned int*)((char*)d_ws + BM_OFF);
    int*          ctab    = (int*)         ((char*)d_ws + CT_OFF);
    float*        prop    = (float*)       ((char*)d_ws + PROP_OFF);
    uint2*        wl      = (uint2*)       ((char*)d_ws + WL_OFF);

    // counter + bitmask -> 0 ; compact table -> -1
    hipMemsetAsync((char*)d_ws + CNT_OFF, 0, BM_OFF - CNT_OFF + 18752, stream);
    hipMemsetAsync((char*)d_ws + CT_OFF, 0xFF, N_NODES * sizeof(int), stream);

    // 12288 waves = 786432 threads -> 3072 blocks of 256
    mark_kernel<<<3072, 256, 0, stream>>>(users, pos, neg, bitmask, ctab, prop);

    // 4,000,000 threads -> 15625 blocks of 256 (exact)
    filter_kernel<<<15625, 256, 0, stream>>>(adj_rows, adj_cols, adj_vals,
                                             bitmask, ctab, counter, wl);

    // 4096 waves -> 1024 blocks of 256
    apply_kernel<<<1024, 256, 0, stream>>>(wl, counter, user_emb, item_emb, prop);

    gather_kernel<<<3072, 256, 0, stream>>>(users, pos, neg,
                                            user_emb, item_emb, ctab, prop, out);
}

// Round 3
// 402.664 us; speedup vs baseline: 2.2376x; 2.2376x over previous
//
#include <hip/hip_runtime.h>

#define N_USER 100000
#define N_ITEM 50000
#define N_NODES 150000
#define EMB 64
#define NNZ 4000000
#define BATCH 4096
#define NSLOTS (3 * BATCH)          // 12288 output slots

// ws layout (bytes):
//   BM_OFF  : bitmask, 150000 bits -> 18752 B (L1-resident during spmm)
//   PROP_OFF: prop table, 150000 x 64 f32 = 38.4 MB (only sampled rows used)
#define BM_OFF   0
#define PROP_OFF 19200

// K1: 16 threads per output slot: zero the sampled node's prop row (float4),
// lane 0 of each group sets the node's bit. Duplicates are idempotent.
__global__ void mark_kernel(const int* __restrict__ users,
                            const int* __restrict__ pos_items,
                            const int* __restrict__ neg_items,
                            unsigned int* __restrict__ bitmask,
                            float* __restrict__ prop) {
    int t = blockIdx.x * blockDim.x + threadIdx.x;   // NSLOTS*16 threads
    int slot = t >> 4;
    int sub = t & 15;
    int k = slot >> 12;
    int i = slot & 4095;
    int node;
    if (k == 0)      node = users[i];
    else if (k == 1) node = N_USER + pos_items[i];
    else             node = N_USER + neg_items[i];
    ((float4*)(prop + (size_t)node * EMB))[sub] = make_float4(0.f, 0.f, 0.f, 0.f);
    if (sub == 0) atomicOr(bitmask + (node >> 5), 1u << (node & 31));
}

// K2: fused filter+apply, one thread per edge.
// Per wave: bitmask test (L1) -> ballot -> in-wave compaction via ds_permute
// -> quarter-waves (16 lanes, float4) process 4 needed edges per iteration.
__global__ void spmm_kernel(const int* __restrict__ rows,
                            const int* __restrict__ cols,
                            const float* __restrict__ vals,
                            const float* __restrict__ user_emb,
                            const float* __restrict__ item_emb,
                            const unsigned int* __restrict__ bitmask,
                            float* __restrict__ prop) {
    int tid = blockIdx.x * blockDim.x + threadIdx.x;   // grid covers NNZ exactly
    int lane = threadIdx.x & 63;
    int row = rows[tid];
    int col = cols[tid];
    float val = vals[tid];

    unsigned int w = bitmask[row >> 5];
    bool needed = (w >> (row & 31)) & 1;
    unsigned long long mask = __ballot(needed);
    if (mask == 0ull) return;                       // wave-uniform
    int cnt = __popcll(mask);

    // In-wave compaction: needed lanes -> positions [0,cnt) (full permutation,
    // non-needed lanes fill [cnt,64) so every lane has a unique destination).
    unsigned long long before = mask & ((1ull << lane) - 1ull);
    int nb = __popcll(before);                      // needed lanes before me
    int pos = needed ? nb : cnt + (lane - nb);
    int addr = pos << 2;                            // ds_permute addr = dstlane*4
    int cr = __builtin_amdgcn_ds_permute(addr, row);
    int cc = __builtin_amdgcn_ds_permute(addr, col);
    int cv = __builtin_amdgcn_ds_permute(addr, __float_as_int(val));

    int group = lane >> 4;                          // 4 quarter-waves
    int gl = lane & 15;                             // 16 lanes * float4 = 256B row
    for (int j = 0; j < cnt; j += 4) {
        int e = j + group;
        bool valid = e < cnt;
        int ee = valid ? e : 0;
        int r = __shfl(cr, ee);
        int c = __shfl(cc, ee);
        float v = __int_as_float(__shfl(cv, ee));
        if (valid) {
            const float4* x = (const float4*)((c < N_USER)
                                ? user_emb + (size_t)c * EMB
                                : item_emb + (size_t)(c - N_USER) * EMB);
            float4 xv = x[gl];
            float* p = prop + (size_t)r * EMB + gl * 4;
            atomicAdd(p + 0, v * xv.x);
            atomicAdd(p + 1, v * xv.y);
            atomicAdd(p + 2, v * xv.z);
            atomicAdd(p + 3, v * xv.w);
        }
    }
}

// K3: out[slot][emb] = (ego + 3*prop)/4, float4 per thread (16 threads/slot)
__global__ void gather_kernel(const int* __restrict__ users,
                              const int* __restrict__ pos_items,
                              const int* __restrict__ neg_items,
                              const float* __restrict__ user_emb,
                              const float* __restrict__ item_emb,
                              const float* __restrict__ prop,
                              float* __restrict__ out) {
    int t = blockIdx.x * blockDim.x + threadIdx.x;   // NSLOTS*16 threads
    int slot = t >> 4;
    int sub = t & 15;
    int k = slot >> 12;
    int i = slot & 4095;
    int node;
    if (k == 0)      node = users[i];
    else if (k == 1) node = N_USER + pos_items[i];
    else             node = N_USER + neg_items[i];
    const float4* ego = (const float4*)((node < N_USER)
                          ? user_emb + (size_t)node * EMB
                          : item_emb + (size_t)(node - N_USER) * EMB);
    float4 e = ego[sub];
    float4 p = ((const float4*)(prop + (size_t)node * EMB))[sub];
    float4 o;
    o.x = (e.x + 3.0f * p.x) * 0.25f;
    o.y = (e.y + 3.0f * p.y) * 0.25f;
    o.z = (e.z + 3.0f * p.z) * 0.25f;
    o.w = (e.w + 3.0f * p.w) * 0.25f;
    ((float4*)out)[t] = o;
}

extern "C" void kernel_launch(void* const* d_in, const int* in_sizes, int n_in,
                              void* d_out, int out_size, void* d_ws, size_t ws_size,
                              hipStream_t stream) {
    const int*   adj_rows = (const int*)  d_in[0];
    const int*   adj_cols = (const int*)  d_in[1];
    const float* adj_vals = (const float*)d_in[2];
    const float* user_emb = (const float*)d_in[3];
    const float* item_emb = (const float*)d_in[4];
    const int*   users    = (const int*)  d_in[5];
    const int*   pos      = (const int*)  d_in[6];
    const int*   neg      = (const int*)  d_in[7];
    float* out = (float*)d_out;

    unsigned int* bitmask = (unsigned int*)((char*)d_ws + BM_OFF);
    float*        prop    = (float*)       ((char*)d_ws + PROP_OFF);

    hipMemsetAsync(bitmask, 0, 18752, stream);

    // NSLOTS*16 = 196608 threads -> 768 blocks of 256
    mark_kernel<<<768, 256, 0, stream>>>(users, pos, neg, bitmask, prop);

    // 4,000,000 threads -> 15625 blocks of 256 (exact)
    spmm_kernel<<<15625, 256, 0, stream>>>(adj_rows, adj_cols, adj_vals,
                                           user_emb, item_emb, bitmask, prop);

    gather_kernel<<<768, 256, 0, stream>>>(users, pos, neg,
                                           user_emb, item_emb, prop, out);
}

// Round 4
// 186.229 us; speedup vs baseline: 4.8381x; 2.1622x over previous
//
#include <hip/hip_runtime.h>

#define N_USER 100000
#define N_ITEM 50000
#define N_NODES 150000
#define EMB 64
#define NNZ 4000000
#define BATCH 4096
#define NSLOTS (3 * BATCH)          // 12288 output slots
#define PF 8                        // edges processed per pipelined batch

// ws layout (bytes):
//   BM_OFF  : bitmask, 150000 bits -> 18752 B (L1-resident during spmm)
//   PROP_OFF: prop table, 150000 x 64 f32 = 38.4 MB (only sampled rows used)
#define BM_OFF   0
#define PROP_OFF 19200

// K1: 16 threads per output slot: zero the sampled node's prop row (float4),
// sub-lane 0 sets the node's bit. Duplicates are idempotent.
__global__ void mark_kernel(const int* __restrict__ users,
                            const int* __restrict__ pos_items,
                            const int* __restrict__ neg_items,
                            unsigned int* __restrict__ bitmask,
                            float* __restrict__ prop) {
    int t = blockIdx.x * blockDim.x + threadIdx.x;   // NSLOTS*16 threads
    int slot = t >> 4;
    int sub = t & 15;
    int k = slot >> 12;
    int i = slot & 4095;
    int node;
    if (k == 0)      node = users[i];
    else if (k == 1) node = N_USER + pos_items[i];
    else             node = N_USER + neg_items[i];
    ((float4*)(prop + (size_t)node * EMB))[sub] = make_float4(0.f, 0.f, 0.f, 0.f);
    if (sub == 0) atomicOr(bitmask + (node >> 5), 1u << (node & 31));
}

// K2: fused filter+apply, one thread per edge.
// Per wave: bitmask test (L1) -> ballot -> ds_permute compaction -> process
// needed edges in batches of PF: issue PF independent 64-lane row gathers,
// THEN the PF full-wave contiguous atomics (one instruction per 256 B row —
// the R3 lesson: atomic HBM write-through is line-granular per instruction).
__global__ void spmm_kernel(const int* __restrict__ rows,
                            const int* __restrict__ cols,
                            const float* __restrict__ vals,
                            const float* __restrict__ user_emb,
                            const float* __restrict__ item_emb,
                            const unsigned int* __restrict__ bitmask,
                            float* __restrict__ prop) {
    int tid = blockIdx.x * blockDim.x + threadIdx.x;   // grid covers NNZ exactly
    int lane = threadIdx.x & 63;
    int row = rows[tid];
    int col = cols[tid];
    float val = vals[tid];

    unsigned int w = bitmask[row >> 5];
    bool needed = (w >> (row & 31)) & 1;
    unsigned long long mask = __ballot(needed);
    if (mask == 0ull) return;                       // wave-uniform
    int cnt = __popcll(mask);

    // In-wave compaction: needed lanes -> positions [0,cnt), others fill the
    // rest so the permutation is total.
    unsigned long long before = mask & ((1ull << lane) - 1ull);
    int nb = __popcll(before);
    int pos = needed ? nb : cnt + (lane - nb);
    int addr = pos << 2;                            // ds_permute: dstlane*4
    int cr = __builtin_amdgcn_ds_permute(addr, row);
    int cc = __builtin_amdgcn_ds_permute(addr, col);
    int cv = __builtin_amdgcn_ds_permute(addr, __float_as_int(val));

    for (int base = 0; base < cnt; base += PF) {    // wave-uniform loop
        float xv[PF]; int rr[PF]; float vv[PF];
        #pragma unroll
        for (int u = 0; u < PF; u++) {
            int e = base + u;
            int ec = e < cnt ? e : cnt - 1;         // clamp tail: dup load, L1 hit
            int c = __shfl(cc, ec);
            rr[u] = __shfl(cr, ec);
            vv[u] = __int_as_float(__shfl(cv, ec));
            const float* x = (c < N_USER) ? user_emb + (size_t)c * EMB
                                          : item_emb + (size_t)(c - N_USER) * EMB;
            xv[u] = x[lane];                        // 64-lane contiguous 256 B
        }
        #pragma unroll
        for (int u = 0; u < PF; u++) {
            if (base + u < cnt)                     // wave-uniform guard
                atomicAdd(prop + (size_t)rr[u] * EMB + lane, vv[u] * xv[u]);
        }
    }
}

// K3: out[slot][emb] = (ego + 3*prop)/4, float4 per thread (16 threads/slot)
__global__ void gather_kernel(const int* __restrict__ users,
                              const int* __restrict__ pos_items,
                              const int* __restrict__ neg_items,
                              const float* __restrict__ user_emb,
                              const float* __restrict__ item_emb,
                              const float* __restrict__ prop,
                              float* __restrict__ out) {
    int t = blockIdx.x * blockDim.x + threadIdx.x;   // NSLOTS*16 threads
    int slot = t >> 4;
    int sub = t & 15;
    int k = slot >> 12;
    int i = slot & 4095;
    int node;
    if (k == 0)      node = users[i];
    else if (k == 1) node = N_USER + pos_items[i];
    else             node = N_USER + neg_items[i];
    const float4* ego = (const float4*)((node < N_USER)
                          ? user_emb + (size_t)node * EMB
                          : item_emb + (size_t)(node - N_USER) * EMB);
    float4 e = ego[sub];
    float4 p = ((const float4*)(prop + (size_t)node * EMB))[sub];
    float4 o;
    o.x = (e.x + 3.0f * p.x) * 0.25f;
    o.y = (e.y + 3.0f * p.y) * 0.25f;
    o.z = (e.z + 3.0f * p.z) * 0.25f;
    o.w = (e.w + 3.0f * p.w) * 0.25f;
    ((float4*)out)[t] = o;
}

extern "C" void kernel_launch(void* const* d_in, const int* in_sizes, int n_in,
                              void* d_out, int out_size, void* d_ws, size_t ws_size,
                              hipStream_t stream) {
    const int*   adj_rows = (const int*)  d_in[0];
    const int*   adj_cols = (const int*)  d_in[1];
    const float* adj_vals = (const float*)d_in[2];
    const float* user_emb = (const float*)d_in[3];
    const float* item_emb = (const float*)d_in[4];
    const int*   users    = (const int*)  d_in[5];
    const int*   pos      = (const int*)  d_in[6];
    const int*   neg      = (const int*)  d_in[7];
    float* out = (float*)d_out;

    unsigned int* bitmask = (unsigned int*)((char*)d_ws + BM_OFF);
    float*        prop    = (float*)       ((char*)d_ws + PROP_OFF);

    hipMemsetAsync(bitmask, 0, 18752, stream);

    // NSLOTS*16 = 196608 threads -> 768 blocks of 256
    mark_kernel<<<768, 256, 0, stream>>>(users, pos, neg, bitmask, prop);

    // 4,000,000 threads -> 15625 blocks of 256 (exact)
    spmm_kernel<<<15625, 256, 0, stream>>>(adj_rows, adj_cols, adj_vals,
                                           user_emb, item_emb, bitmask, prop);

    gather_kernel<<<768, 256, 0, stream>>>(users, pos, neg,
                                           user_emb, item_emb, prop, out);
}

// Round 5
// 171.793 us; speedup vs baseline: 5.2447x; 1.0840x over previous
//
#include <hip/hip_runtime.h>

#define N_USER 100000
#define N_ITEM 50000
#define N_NODES 150000
#define EMB 64
#define NNZ 4000000
#define BATCH 4096
#define NSLOTS (3 * BATCH)          // 12288 output slots / compact ids
#define CAP 128                     // bucket capacity per compact row (λ≈26.7)

// ws layout (bytes, 256-aligned):
//   BM_OFF : bitmask, 150000 bits -> 18752 B (L1-resident during scatter)
//   CUR_OFF: per-compact-row cursors, 12288 u32 = 49152 B
//   CT_OFF : node -> compact id, 150000 i32 = 600000 B (init -1)
//   PROP_OFF: compact prop, 12288 x 64 f32 = 3 MB
//   BKT_OFF : buckets, 12288 x CAP x 8 B = 12.6 MB
#define BM_OFF   0
#define CUR_OFF  19200
#define CT_OFF   68352
#define PROP_OFF 668416
#define BKT_OFF  3814144

// K1: one thread per output slot: set node bit, claim compact id (CAS winner).
__global__ void mark_kernel(const int* __restrict__ users,
                            const int* __restrict__ pos_items,
                            const int* __restrict__ neg_items,
                            unsigned int* __restrict__ bitmask,
                            int* __restrict__ ctab) {
    int t = blockIdx.x * blockDim.x + threadIdx.x;   // NSLOTS threads
    int k = t >> 12;
    int i = t & 4095;
    int node;
    if (k == 0)      node = users[i];
    else if (k == 1) node = N_USER + pos_items[i];
    else             node = N_USER + neg_items[i];
    atomicOr(bitmask + (node >> 5), 1u << (node & 31));
    atomicCAS(ctab + node, -1, t);
}

// K2: stream 4M edges; ~8% needed edges drop an 8 B (col,val) record into
// their row's bucket. No embedding gather, no prop atomics in this pass.
__global__ void scatter_kernel(const int* __restrict__ rows,
                               const int* __restrict__ cols,
                               const float* __restrict__ vals,
                               const unsigned int* __restrict__ bitmask,
                               const int* __restrict__ ctab,
                               unsigned int* __restrict__ cursor,
                               uint2* __restrict__ bucket) {
    int tid = blockIdx.x * blockDim.x + threadIdx.x;   // grid covers NNZ exactly
    int row = rows[tid];
    int col = cols[tid];
    float val = vals[tid];
    unsigned int w = bitmask[row >> 5];
    if ((w >> (row & 31)) & 1) {
        int cid = ctab[row];
        unsigned int pos = atomicAdd(cursor + cid, 1u);
        if (pos < CAP)                                  // overflow guard (P~1e-40)
            bucket[(size_t)cid * CAP + pos] =
                make_uint2((unsigned int)col, __float_as_uint(val));
    }
}

// K3: one wave per compact row: accumulate its bucket entries in registers,
// one plain 256 B store. Entry loads are wave-uniform (scalar path); the 8
// per-iteration embedding gathers are independent -> latency pipelined.
__global__ void accum_kernel(const unsigned int* __restrict__ cursor,
                             const uint2* __restrict__ bucket,
                             const float* __restrict__ user_emb,
                             const float* __restrict__ item_emb,
                             float* __restrict__ prop) {
    int t = blockIdx.x * blockDim.x + threadIdx.x;     // NSLOTS waves
    int wv = t >> 6;
    int lane = t & 63;
    unsigned int n = cursor[wv];
    if (n > CAP) n = CAP;
    const uint2* bkt = bucket + (size_t)wv * CAP;
    float acc = 0.0f;
    for (unsigned int base = 0; base < n; base += 8) {
        #pragma unroll
        for (int u = 0; u < 8; u++) {
            unsigned int e = base + (unsigned int)u;
            uint2 ev = bkt[e < n ? e : n - 1];          // wave-uniform address
            int c = (int)ev.x;
            float v = __uint_as_float(ev.y);
            const float* x = (c < N_USER) ? user_emb + (size_t)c * EMB
                                          : item_emb + (size_t)(c - N_USER) * EMB;
            float xv = x[lane];                         // 64-lane 256 B gather
            acc += (e < n) ? v * xv : 0.0f;
        }
    }
    prop[(size_t)wv * EMB + lane] = acc;                // zero rows stay zero
}

// K4: out[slot][emb] = (ego + 3*prop[cid])/4, float4 per thread
__global__ void gather_kernel(const int* __restrict__ users,
                              const int* __restrict__ pos_items,
                              const int* __restrict__ neg_items,
                              const float* __restrict__ user_emb,
                              const float* __restrict__ item_emb,
                              const int* __restrict__ ctab,
                              const float* __restrict__ prop,
                              float* __restrict__ out) {
    int t = blockIdx.x * blockDim.x + threadIdx.x;     // NSLOTS*16 threads
    int slot = t >> 4;
    int sub = t & 15;
    int k = slot >> 12;
    int i = slot & 4095;
    int node;
    if (k == 0)      node = users[i];
    else if (k == 1) node = N_USER + pos_items[i];
    else             node = N_USER + neg_items[i];
    const float4* ego = (const float4*)((node < N_USER)
                          ? user_emb + (size_t)node * EMB
                          : item_emb + (size_t)(node - N_USER) * EMB);
    float4 e = ego[sub];
    int cid = ctab[node];
    float4 p = ((const float4*)(prop + (size_t)cid * EMB))[sub];
    float4 o;
    o.x = (e.x + 3.0f * p.x) * 0.25f;
    o.y = (e.y + 3.0f * p.y) * 0.25f;
    o.z = (e.z + 3.0f * p.z) * 0.25f;
    o.w = (e.w + 3.0f * p.w) * 0.25f;
    ((float4*)out)[t] = o;
}

extern "C" void kernel_launch(void* const* d_in, const int* in_sizes, int n_in,
                              void* d_out, int out_size, void* d_ws, size_t ws_size,
                              hipStream_t stream) {
    const int*   adj_rows = (const int*)  d_in[0];
    const int*   adj_cols = (const int*)  d_in[1];
    const float* adj_vals = (const float*)d_in[2];
    const float* user_emb = (const float*)d_in[3];
    const float* item_emb = (const float*)d_in[4];
    const int*   users    = (const int*)  d_in[5];
    const int*   pos      = (const int*)  d_in[6];
    const int*   neg      = (const int*)  d_in[7];
    float* out = (float*)d_out;

    unsigned int* bitmask = (unsigned int*)((char*)d_ws + BM_OFF);
    unsigned int* cursor  = (unsigned int*)((char*)d_ws + CUR_OFF);
    int*          ctab    = (int*)         ((char*)d_ws + CT_OFF);
    float*        prop    = (float*)       ((char*)d_ws + PROP_OFF);
    uint2*        bucket  = (uint2*)       ((char*)d_ws + BKT_OFF);

    hipMemsetAsync((char*)d_ws + BM_OFF, 0, CT_OFF, stream);          // bitmask+cursors
    hipMemsetAsync((char*)d_ws + CT_OFF, 0xFF, N_NODES * 4, stream);  // ctab = -1

    // NSLOTS = 12288 threads -> 48 blocks of 256
    mark_kernel<<<48, 256, 0, stream>>>(users, pos, neg, bitmask, ctab);

    // 4,000,000 threads -> 15625 blocks of 256 (exact)
    scatter_kernel<<<15625, 256, 0, stream>>>(adj_rows, adj_cols, adj_vals,
                                              bitmask, ctab, cursor, bucket);

    // NSLOTS waves = 786432 threads -> 3072 blocks of 256
    accum_kernel<<<3072, 256, 0, stream>>>(cursor, bucket, user_emb, item_emb, prop);

    // NSLOTS*16 = 196608 threads -> 768 blocks of 256
    gather_kernel<<<768, 256, 0, stream>>>(users, pos, neg,
                                           user_emb, item_emb, ctab, prop, out);
}